// Round 6
// baseline (382.714 us; speedup 1.0000x reference)
//
#include <hip/hip_runtime.h>
#include <hip/hip_bf16.h>

// GraphSAGE 3-layer: pool(64->64) -> pool(64->32) -> mean(32->32)
// R6: (1) gathers load 16B/lane (8 rows per wave-load max / 16 rows sum) --
// half the instructions per edge vs R5; (2) CSR pairs packed to 32b
// ((src<<S)|dst_local) halving pairs traffic; (3) layer1-second MM fused with
// layer2-pool MM via LDS tile (kills one launch + 12.8MB h1 re-read).

typedef unsigned int uint;
typedef short short8 __attribute__((ext_vector_type(8)));
typedef float f32x4 __attribute__((ext_vector_type(4)));

__device__ __forceinline__ float bf2f(unsigned short h){
  return __uint_as_float(((uint)h) << 16);
}
__device__ __forceinline__ unsigned short f2bf(float f){
  uint u = __float_as_uint(f);
  u += 0x7fffu + ((u >> 16) & 1u);   // RNE
  return (unsigned short)(u >> 16);
}
__device__ __forceinline__ float lo16(uint u){ return __uint_as_float(u << 16); }
__device__ __forceinline__ float hi16(uint u){ return __uint_as_float(u & 0xffff0000u); }

// flags[0]=1 if float inputs bf16 else f32; flags[1]=1 if edge_index int64.
// Also zeroes chist (saves a memset launch).
__global__ void detect_kernel(const unsigned short* x, const int* ei, int* flags,
                              uint* chist){
  int lane = threadIdx.x;  // 64 threads
  for (int i = lane; i < 1024; i += 64) chist[i] = 0;
  int sane = 0;
  #pragma unroll
  for (int k = 0; k < 4; ++k){
    int e = (x[(lane * 4 + k) * 2] >> 7) & 0xff;
    sane += (e >= 118 && e <= 134);
  }
  #pragma unroll
  for (int off = 32; off; off >>= 1) sane += __shfl_down(sane, off, 64);
  unsigned long long b = __ballot(ei[1 + 2 * lane] != 0);
  if (lane == 0){ flags[0] = (sane >= 128); flags[1] = (b == 0ull); }
}

// ---------------- weight prep: bf16 + transpose to WT[C][K] ----------------
struct WConv {
  const void* src[13];
  int n[13], isbias[13], Cs[13], K[13], off[13];
};

__global__ void conv_w(WConv wc, unsigned short* wtbase, float* bbase,
                       const int* flags){
  int t = blockIdx.x, n = wc.n[t];
  int isbf = flags[0];
  if (wc.isbias[t]){
    float* d = bbase + wc.off[t];
    for (int i = threadIdx.x; i < n; i += blockDim.x)
      d[i] = isbf ? bf2f(((const unsigned short*)wc.src[t])[i])
                  : ((const float*)wc.src[t])[i];
  } else {
    unsigned short* d = wtbase + wc.off[t];
    int Cs = wc.Cs[t], K = wc.K[t], Cm = (1 << Cs) - 1;
    for (int i = threadIdx.x; i < n; i += blockDim.x){
      int k = i >> Cs, c = i & Cm;
      unsigned short v = isbf ? ((const unsigned short*)wc.src[t])[i]
                              : f2bf(((const float*)wc.src[t])[i]);
      d[c * K + k] = v;
    }
  }
}

__device__ __forceinline__ void load_edge(const void* ei, int E, int is64, int e,
                                          int& s, int& d){
  if (is64){
    const long long* p = (const long long*)ei;
    s = (int)p[e]; d = (int)p[E + e];
  } else {
    const int* p = (const int*)ei;
    s = p[e]; d = p[E + e];
  }
}

// ---------------- CSR build ----------------
#define CSR_CE 8192

__global__ __launch_bounds__(256) void csr_phase0(
    const void* __restrict__ ei, const int* __restrict__ flags,
    uint* __restrict__ chist, int E, int N, int NB, int S)
{
  __shared__ uint h[1024];
  int is64 = flags[1], t = threadIdx.x;
  int e0 = blockIdx.x * CSR_CE;
  for (int i = t; i < 1024; i += 256) h[i] = 0;
  __syncthreads();
  #pragma unroll 4
  for (int it = 0; it < CSR_CE / 256; ++it){
    int e = e0 + it * 256 + t;
    if (e >= E) break;
    int s, d; load_edge(ei, E, is64, e, s, d);
    if ((unsigned)s >= (unsigned)N || (unsigned)d >= (unsigned)N) continue;
    atomicAdd(&h[d >> S], 1u);
  }
  __syncthreads();
  for (int i = t; i < NB; i += 256){ uint c = h[i]; if (c) atomicAdd(chist + i, c); }
}

__global__ void csr_scan0(const uint* __restrict__ chist, int* __restrict__ cbase,
                          int* __restrict__ ccur, int* __restrict__ rowptrN, int NB)
{
  __shared__ int sm[256];
  int t = threadIdx.x;
  int g = (NB + 255) / 256;          // <= 4
  int vb = t * g, v[4], s = 0;
  for (int k = 0; k < g; ++k){
    int i = vb + k; int x = (i < NB) ? (int)chist[i] : 0; v[k] = x; s += x;
  }
  sm[t] = s; __syncthreads();
  for (int off = 1; off < 256; off <<= 1){
    int x = (t >= off) ? sm[t - off] : 0;
    __syncthreads(); sm[t] += x; __syncthreads();
  }
  int run = sm[t] - s;
  for (int k = 0; k < g; ++k){
    int i = vb + k;
    if (i < NB){ cbase[i] = run; ccur[i] = run; run += v[k]; }
  }
  if (t == 255){ cbase[NB] = run; *rowptrN = run; }
}

// phase1: multisplit to coarse buckets; packed pair = (src<<S)|(dst&(2^S-1)).
__global__ __launch_bounds__(256) void csr_phase1(
    const void* __restrict__ ei, const int* __restrict__ flags,
    int* __restrict__ ccur, uint* __restrict__ pairs,
    int E, int N, int NB, int S)
{
  __shared__ uint hist[1024];
  __shared__ uint gbase[1024];
  int is64 = flags[1];
  int t = threadIdx.x;
  uint dmask = (1u << S) - 1u;
  int e0 = blockIdx.x * CSR_CE;
  for (int i = t; i < 1024; i += 256) hist[i] = 0;
  __syncthreads();
  #pragma unroll 4
  for (int it = 0; it < CSR_CE / 256; ++it){
    int e = e0 + it * 256 + t;
    if (e >= E) break;
    int s, d; load_edge(ei, E, is64, e, s, d);
    if ((unsigned)s >= (unsigned)N || (unsigned)d >= (unsigned)N) continue;
    atomicAdd(&hist[d >> S], 1u);
  }
  __syncthreads();
  for (int b = t; b < NB; b += 256){
    uint c = hist[b];
    if (c) gbase[b] = (uint)atomicAdd(&ccur[b], (int)c);
    hist[b] = 0;
  }
  __syncthreads();
  #pragma unroll 4
  for (int it = 0; it < CSR_CE / 256; ++it){
    int e = e0 + it * 256 + t;
    if (e >= E) break;
    int s, d; load_edge(ei, E, is64, e, s, d);
    if ((unsigned)s >= (unsigned)N || (unsigned)d >= (unsigned)N) continue;
    int b = d >> S;
    uint local = atomicAdd(&hist[b], 1u);
    pairs[gbase[b] + local] = ((uint)s << S) | ((uint)d & dmask);
  }
}

// phase2: per-bucket hist+scan in LDS -> row_ptr slice, exact placement.
#define P2_CAP 6144
__global__ __launch_bounds__(256) void csr_phase2(
    const int* __restrict__ cbase, const uint* __restrict__ pairs,
    int* __restrict__ bucket, int* __restrict__ row_ptr, int N, int S)
{
  __shared__ int lbuf[P2_CAP];
  __shared__ int cur[1024];
  __shared__ int sm[256];
  int b = blockIdx.x, t = threadIdx.x;
  uint dmask = (1u << S) - 1u;
  int n0 = b << S;
  int n1 = n0 + (1 << S); if (n1 > N) n1 = N;
  int nn = n1 - n0;
  int base = cbase[b], end = cbase[b + 1], cnt = end - base;

  for (int i = t; i < nn; i += 256) cur[i] = 0;
  __syncthreads();
  for (int j = base + t; j < end; j += 256)
    atomicAdd(&cur[(int)(pairs[j] & dmask)], 1);
  __syncthreads();
  int g = (nn + 255) / 256, vb = t * g, v[4], s = 0;
  for (int k = 0; k < g; ++k){
    int i = vb + k; int x = (i < nn) ? cur[i] : 0; v[k] = x; s += x;
  }
  sm[t] = s; __syncthreads();
  for (int off = 1; off < 256; off <<= 1){
    int x = (t >= off) ? sm[t - off] : 0;
    __syncthreads(); sm[t] += x; __syncthreads();
  }
  int run = sm[t] - s;
  for (int k = 0; k < g; ++k){
    int i = vb + k;
    if (i < nn){ row_ptr[n0 + i] = base + run; cur[i] = run; run += v[k]; }
  }
  __syncthreads();
  if (cnt <= 0) return;
  if (cnt <= P2_CAP){
    for (int j = base + t; j < end; j += 256){
      uint pr = pairs[j];
      int pos = atomicAdd(&cur[(int)(pr & dmask)], 1);
      lbuf[pos] = (int)(pr >> S);
    }
    __syncthreads();
    for (int i = t; i < cnt; i += 256) bucket[base + i] = lbuf[i];
  } else {
    for (int j = base + t; j < end; j += 256){
      uint pr = pairs[j];
      int pos = atomicAdd(&cur[(int)(pr & dmask)], 1);
      bucket[base + pos] = (int)(pr >> S);
    }
  }
}

// ---------------- gather-reduce (16B/lane) ----------------
// wave per node. fg8=(lane&7)*8 features (uint4=16B); rowsel=lane>>3 ->
// 8 full 128B rows per load instruction.
__global__ __launch_bounds__(256) void gather_max64(
    const int* __restrict__ row_ptr, const int* __restrict__ bucket,
    const unsigned short* __restrict__ m, unsigned short* __restrict__ agg, int N)
{
  int node = (int)((blockIdx.x * 256u + threadIdx.x) >> 6);
  int lane = threadIdx.x & 63;
  if (node >= N) return;
  int rs = row_ptr[node], cnt = row_ptr[node + 1] - rs;
  int fg8 = (lane & 7) * 8, rowsel = lane >> 3;
  float a0 = 0.f, a1 = 0.f, a2 = 0.f, a3 = 0.f;
  float a4 = 0.f, a5 = 0.f, a6 = 0.f, a7 = 0.f;
  for (int c0 = 0; c0 < cnt; c0 += 64){
    int chunk = min(cnt - c0, 64);
    int bval = (lane < chunk) ? bucket[rs + c0 + lane] : 0;
    int j = 0;
    for (; j + 8 <= chunk; j += 8){
      int s = __shfl(bval, j + rowsel, 64);
      uint4 v = *(const uint4*)(m + (size_t)s * 64 + fg8);
      a0 = fmaxf(a0, lo16(v.x)); a1 = fmaxf(a1, hi16(v.x));
      a2 = fmaxf(a2, lo16(v.y)); a3 = fmaxf(a3, hi16(v.y));
      a4 = fmaxf(a4, lo16(v.z)); a5 = fmaxf(a5, hi16(v.z));
      a6 = fmaxf(a6, lo16(v.w)); a7 = fmaxf(a7, hi16(v.w));
    }
    if (j < chunk){
      int jj = j + rowsel;
      int s = __shfl(bval, jj < chunk ? jj : j, 64);
      if (jj < chunk){
        uint4 v = *(const uint4*)(m + (size_t)s * 64 + fg8);
        a0 = fmaxf(a0, lo16(v.x)); a1 = fmaxf(a1, hi16(v.x));
        a2 = fmaxf(a2, lo16(v.y)); a3 = fmaxf(a3, hi16(v.y));
        a4 = fmaxf(a4, lo16(v.z)); a5 = fmaxf(a5, hi16(v.z));
        a6 = fmaxf(a6, lo16(v.w)); a7 = fmaxf(a7, hi16(v.w));
      }
    }
  }
  #pragma unroll
  for (int off = 8; off <= 32; off <<= 1){
    a0 = fmaxf(a0, __shfl_xor(a0, off, 64));
    a1 = fmaxf(a1, __shfl_xor(a1, off, 64));
    a2 = fmaxf(a2, __shfl_xor(a2, off, 64));
    a3 = fmaxf(a3, __shfl_xor(a3, off, 64));
    a4 = fmaxf(a4, __shfl_xor(a4, off, 64));
    a5 = fmaxf(a5, __shfl_xor(a5, off, 64));
    a6 = fmaxf(a6, __shfl_xor(a6, off, 64));
    a7 = fmaxf(a7, __shfl_xor(a7, off, 64));
  }
  if (lane < 8){
    uint4 pk;
    pk.x = (uint)f2bf(a0) | ((uint)f2bf(a1) << 16);
    pk.y = (uint)f2bf(a2) | ((uint)f2bf(a3) << 16);
    pk.z = (uint)f2bf(a4) | ((uint)f2bf(a5) << 16);
    pk.w = (uint)f2bf(a6) | ((uint)f2bf(a7) << 16);
    *(uint4*)(agg + (size_t)node * 64 + fg8) = pk;
  }
}

// wave per node; 64B rows. fg8=(lane&3)*8; rowsel=lane>>2 -> 16 rows/load.
__global__ __launch_bounds__(256) void gather_sum32(
    const int* __restrict__ row_ptr, const int* __restrict__ bucket,
    const unsigned short* __restrict__ h2, unsigned short* __restrict__ ssum, int N)
{
  int node = (int)((blockIdx.x * 256u + threadIdx.x) >> 6);
  int lane = threadIdx.x & 63;
  if (node >= N) return;
  int rs = row_ptr[node], cnt = row_ptr[node + 1] - rs;
  int fg8 = (lane & 3) * 8, rowsel = lane >> 2;
  float a0 = 0.f, a1 = 0.f, a2 = 0.f, a3 = 0.f;
  float a4 = 0.f, a5 = 0.f, a6 = 0.f, a7 = 0.f;
  for (int c0 = 0; c0 < cnt; c0 += 64){
    int chunk = min(cnt - c0, 64);
    int bval = (lane < chunk) ? bucket[rs + c0 + lane] : 0;
    int j = 0;
    for (; j + 16 <= chunk; j += 16){
      int s = __shfl(bval, j + rowsel, 64);
      uint4 v = *(const uint4*)(h2 + (size_t)s * 32 + fg8);
      a0 += lo16(v.x); a1 += hi16(v.x); a2 += lo16(v.y); a3 += hi16(v.y);
      a4 += lo16(v.z); a5 += hi16(v.z); a6 += lo16(v.w); a7 += hi16(v.w);
    }
    if (j < chunk){
      int jj = j + rowsel;
      int s = __shfl(bval, jj < chunk ? jj : j, 64);
      if (jj < chunk){
        uint4 v = *(const uint4*)(h2 + (size_t)s * 32 + fg8);
        a0 += lo16(v.x); a1 += hi16(v.x); a2 += lo16(v.y); a3 += hi16(v.y);
        a4 += lo16(v.z); a5 += hi16(v.z); a6 += lo16(v.w); a7 += hi16(v.w);
      }
    }
  }
  #pragma unroll
  for (int off = 4; off <= 32; off <<= 1){
    a0 += __shfl_xor(a0, off, 64); a1 += __shfl_xor(a1, off, 64);
    a2 += __shfl_xor(a2, off, 64); a3 += __shfl_xor(a3, off, 64);
    a4 += __shfl_xor(a4, off, 64); a5 += __shfl_xor(a5, off, 64);
    a6 += __shfl_xor(a6, off, 64); a7 += __shfl_xor(a7, off, 64);
  }
  if (lane < 4){
    uint4 pk;
    pk.x = (uint)f2bf(a0) | ((uint)f2bf(a1) << 16);
    pk.y = (uint)f2bf(a2) | ((uint)f2bf(a3) << 16);
    pk.z = (uint)f2bf(a4) | ((uint)f2bf(a5) << 16);
    pk.w = (uint)f2bf(a6) | ((uint)f2bf(a7) << 16);
    *(uint4*)(ssum + (size_t)node * 32 + fg8) = pk;
  }
}

// ---------------- MFMA dense transforms ----------------
__device__ __forceinline__ short8 ld_fragA_bf16(const unsigned short* A, int row,
                                                int K, int koff){
  return *(const short8*)(A + (size_t)row * K + koff);
}
__device__ __forceinline__ short8 ld_fragA_f32(const float* A, int row,
                                               int K, int koff){
  const float* q = A + (size_t)row * K + koff;
  float4 f0 = *(const float4*)q;
  float4 f1 = *(const float4*)(q + 4);
  short8 r;
  r[0] = (short)f2bf(f0.x); r[1] = (short)f2bf(f0.y);
  r[2] = (short)f2bf(f0.z); r[3] = (short)f2bf(f0.w);
  r[4] = (short)f2bf(f1.x); r[5] = (short)f2bf(f1.y);
  r[6] = (short)f2bf(f1.z); r[7] = (short)f2bf(f1.w);
  return r;
}

// KA in {32,64}; KB in {0,32,64}; CT = C/16 in {2,4}; AMODE: 0=bf16, 2=runtime.
template<int KA, int KB, int CT, bool RELU, bool MEAN, bool OUTF32, int AMODE>
__global__ __launch_bounds__(256) void mfma_mm(
    const void* __restrict__ Av, const unsigned short* __restrict__ Bv,
    const unsigned short* __restrict__ WaT, const unsigned short* __restrict__ WbT,
    const float* __restrict__ bias, const int* __restrict__ row_ptr,
    const int* __restrict__ flags, void* __restrict__ outv, int N)
{
  constexpr int C = CT * 16;
  int wid = threadIdx.x >> 6, lane = threadIdx.x & 63;
  int g = blockIdx.x * 4 + wid;
  int rt, ct;
  if constexpr (CT == 4){ rt = g >> 2; ct = g & 3; }
  else                  { rt = g >> 1; ct = g & 1; }
  int RT = (N + 15) >> 4;
  if (rt >= RT) return;
  int m = lane & 15, quad = lane >> 4;
  int row = rt * 16 + m;
  int rowc = row < N ? row : N - 1;
  int colbase = ct * 16;
  int koq = quad * 8;

  bool af32 = (AMODE == 2) && (flags[0] == 0);
  f32x4 accS = {0.f, 0.f, 0.f, 0.f};
  f32x4 accA = {0.f, 0.f, 0.f, 0.f};

  #pragma unroll
  for (int k0 = 0; k0 < KA; k0 += 32){
    short8 af = af32 ? ld_fragA_f32((const float*)Av, rowc, KA, k0 + koq)
                     : ld_fragA_bf16((const unsigned short*)Av, rowc, KA, k0 + koq);
    short8 wf = *(const short8*)(WaT + (size_t)(colbase + m) * KA + k0 + koq);
    accS = __builtin_amdgcn_mfma_f32_16x16x32_bf16(af, wf, accS, 0, 0, 0);
  }
  if constexpr (KB > 0){
    #pragma unroll
    for (int k0 = 0; k0 < KB; k0 += 32){
      short8 bf = ld_fragA_bf16(Bv, rowc, KB, k0 + koq);
      short8 wf = *(const short8*)(WbT + (size_t)(colbase + m) * KB + k0 + koq);
      if constexpr (MEAN)
        accA = __builtin_amdgcn_mfma_f32_16x16x32_bf16(bf, wf, accA, 0, 0, 0);
      else
        accS = __builtin_amdgcn_mfma_f32_16x16x32_bf16(bf, wf, accS, 0, 0, 0);
    }
  }
  float bv = bias[colbase + m];
  #pragma unroll
  for (int r = 0; r < 4; ++r){
    int orow = rt * 16 + quad * 4 + r;
    if (orow >= N) continue;
    float v = accS[r] + bv;
    if constexpr (MEAN){
      int dg = row_ptr[orow + 1] - row_ptr[orow];
      v += accA[r] * (1.f / fmaxf((float)dg, 1.f));
    }
    if constexpr (RELU) v = fmaxf(v, 0.f);
    if constexpr (OUTF32)
      ((float*)outv)[(size_t)orow * C + colbase + m] = v;
    else
      ((unsigned short*)outv)[(size_t)orow * C + colbase + m] = f2bf(v);
  }
}

// Fused: h1 = relu(A@WaT^T + B@WbT^T + b1) [C=64, bf16 out1], then
// mbuf2 = relu(h1@WcT^T + b2p) [C=64, bf16 out2]. Block = 4 waves = one
// 16-row tile; h1 tile round-trips through LDS (C/D -> A-frag layout).
template<int AMODE>
__global__ __launch_bounds__(256) void mfma_mm_fused(
    const void* __restrict__ Av, const unsigned short* __restrict__ Bv,
    const unsigned short* __restrict__ WaT, const unsigned short* __restrict__ WbT,
    const float* __restrict__ bias1,
    const unsigned short* __restrict__ WcT, const float* __restrict__ bias2,
    const int* __restrict__ flags,
    unsigned short* __restrict__ out1, unsigned short* __restrict__ out2, int N)
{
  constexpr int K = 64, C = 64, LDH = 72;   // 144B row stride: 16B-aligned
  __shared__ unsigned short hl[16 * LDH];
  int wid = threadIdx.x >> 6, lane = threadIdx.x & 63;
  int rt = blockIdx.x;
  int m = lane & 15, quad = lane >> 4;
  int row = rt * 16 + m;
  int rowc = row < N ? row : N - 1;
  int colbase = wid * 16;
  int koq = quad * 8;
  bool af32 = (AMODE == 2) && (flags[0] == 0);

  f32x4 acc = {0.f, 0.f, 0.f, 0.f};
  #pragma unroll
  for (int k0 = 0; k0 < K; k0 += 32){
    short8 af = af32 ? ld_fragA_f32((const float*)Av, rowc, K, k0 + koq)
                     : ld_fragA_bf16((const unsigned short*)Av, rowc, K, k0 + koq);
    short8 wf = *(const short8*)(WaT + (size_t)(colbase + m) * K + k0 + koq);
    acc = __builtin_amdgcn_mfma_f32_16x16x32_bf16(af, wf, acc, 0, 0, 0);
    short8 bf = ld_fragA_bf16(Bv, rowc, K, k0 + koq);
    short8 wg = *(const short8*)(WbT + (size_t)(colbase + m) * K + k0 + koq);
    acc = __builtin_amdgcn_mfma_f32_16x16x32_bf16(bf, wg, acc, 0, 0, 0);
  }
  float bv = bias1[colbase + m];
  #pragma unroll
  for (int r = 0; r < 4; ++r){
    int rl = quad * 4 + r;
    int orow = rt * 16 + rl;
    unsigned short hb = f2bf(fmaxf(acc[r] + bv, 0.f));
    hl[rl * LDH + colbase + m] = hb;
    if (orow < N) out1[(size_t)orow * C + colbase + m] = hb;
  }
  __syncthreads();
  f32x4 acc2 = {0.f, 0.f, 0.f, 0.f};
  #pragma unroll
  for (int k0 = 0; k0 < K; k0 += 32){
    short8 af = *(const short8*)(hl + m * LDH + k0 + koq);
    short8 wf = *(const short8*)(WcT + (size_t)(colbase + m) * K + k0 + koq);
    acc2 = __builtin_amdgcn_mfma_f32_16x16x32_bf16(af, wf, acc2, 0, 0, 0);
  }
  float b2v = bias2[colbase + m];
  #pragma unroll
  for (int r = 0; r < 4; ++r){
    int orow = rt * 16 + quad * 4 + r;
    if (orow < N)
      out2[(size_t)orow * C + colbase + m] = f2bf(fmaxf(acc2[r] + b2v, 0.f));
  }
}

static inline char* align256(char* p){
  return (char*)(((uintptr_t)p + 255) & ~(uintptr_t)255);
}

extern "C" void kernel_launch(void* const* d_in, const int* in_sizes, int n_in,
                              void* d_out, int out_size, void* d_ws, size_t ws_size,
                              hipStream_t stream)
{
  const void* x = d_in[0];
  const void* ei = d_in[1];
  int N = in_sizes[0] / 64;   // 100000
  int E = in_sizes[1] / 2;    // 1600000

  char* ws = (char*)d_ws;
  unsigned short* wtbase = (unsigned short*)ws;     // 22528 ushorts (45KB)
  float* bbase = (float*)(ws + 65536);              // 256 floats
  int* flags = (int*)(ws + 131072 - 256);

  int S = 7, NB = (N + 127) >> 7;
  while (NB > 1024){ S++; NB = (N + (1 << S) - 1) >> S; }

  char* p = ws + 131072;
  int* row_ptr = (int*)p; p = align256(p + (size_t)(N + 1) * 4);
  uint* chist  = (uint*)p; p = align256(p + 4352);
  int* cbase   = (int*)p; p = align256(p + 4352);
  int* ccur    = (int*)p; p = align256(p + 4352);
  int* bucket  = (int*)p; p = align256(p + (size_t)E * 4);
  char* P = p;  p = align256(p + (size_t)N * 64 * 2);   // pairs(E*4)/mbuf/h2
  char* Q = p;  p = align256(p + (size_t)N * 64 * 2);   // aggb/ssum
  char* R = p;  p = align256(p + (size_t)N * 64 * 2);   // h1
  uint* pairs = (uint*)P;                               // E*4 <= N*128
  unsigned short* mbuf = (unsigned short*)P;
  unsigned short* h2   = (unsigned short*)P;   // after mbuf dead
  unsigned short* aggb = (unsigned short*)Q;
  unsigned short* ssum = (unsigned short*)Q;   // after aggb dead
  unsigned short* h1   = (unsigned short*)R;

  hipLaunchKernelGGL(detect_kernel, dim3(1), dim3(64), 0, stream,
                     (const unsigned short*)x, (const int*)ei, flags, chist);

  WConv wc;
  {
    const int widx[13] = {2, 3, 4, 5, 6, 7, 8, 9, 10, 11, 12, 13, 14};
    const int isb[13]  = {0, 1, 0, 0, 1, 0, 1, 0, 0, 1, 0, 0, 1};
    const int Cs[13]   = {6, 0, 6, 6, 0, 6, 0, 5, 5, 0, 5, 5, 0};
    const int Kk[13]   = {64, 0, 64, 64, 0, 64, 0, 64, 64, 0, 32, 32, 0};
    const int off[13]  = {0, 0, 4096, 8192, 64, 12288, 128, 16384, 18432, 192,
                          20480, 21504, 224};
    for (int i = 0; i < 13; ++i){
      wc.src[i] = d_in[widx[i]]; wc.n[i] = in_sizes[widx[i]];
      wc.isbias[i] = isb[i]; wc.Cs[i] = Cs[i]; wc.K[i] = Kk[i]; wc.off[i] = off[i];
    }
  }
  hipLaunchKernelGGL(conv_w, dim3(13), dim3(256), 0, stream, wc, wtbase, bbase, flags);
  unsigned short* W1pT = wtbase + 0;     unsigned short* W1sT = wtbase + 4096;
  unsigned short* W1nT = wtbase + 8192;  unsigned short* W2pT = wtbase + 12288;
  unsigned short* W2sT = wtbase + 16384; unsigned short* W2nT = wtbase + 18432;
  unsigned short* W3sT = wtbase + 20480; unsigned short* W3nT = wtbase + 21504;
  float* b1p = bbase + 0;  float* b1 = bbase + 64; float* b2p = bbase + 128;
  float* b2 = bbase + 192; float* b3 = bbase + 224;

  // ---- CSR build ----
  int nP = (E + CSR_CE - 1) / CSR_CE;
  csr_phase0<<<nP, 256, 0, stream>>>(ei, flags, chist, E, N, NB, S);
  csr_scan0<<<1, 256, 0, stream>>>(chist, cbase, ccur, row_ptr + N, NB);
  csr_phase1<<<nP, 256, 0, stream>>>(ei, flags, ccur, pairs, E, N, NB, S);
  csr_phase2<<<NB, 256, 0, stream>>>(cbase, pairs, bucket, row_ptr, N, S);

  int RT = (N + 15) / 16;
  int gc2 = (RT * 2 + 3) / 4;   // CT=2 kernels
  int gg = (N + 3) / 4;         // gathers: 4 nodes (waves) per block

  // ---- layer 1 (pool 64->64, relu) + layer-2 pool transform fused ----
  mfma_mm<64,0,4,true,false,false,2><<<RT,256,0,stream>>>(
      x, nullptr, W1pT, nullptr, b1p, nullptr, flags, mbuf, N);
  gather_max64<<<gg,256,0,stream>>>(row_ptr, bucket, mbuf, aggb, N);
  mfma_mm_fused<2><<<RT,256,0,stream>>>(
      x, aggb, W1sT, W1nT, b1, W2pT, b2p, flags, h1, mbuf, N);

  // ---- layer 2 (pool 64->32) ----
  gather_max64<<<gg,256,0,stream>>>(row_ptr, bucket, mbuf, aggb, N);
  mfma_mm<64,64,2,false,false,false,0><<<gc2,256,0,stream>>>(
      h1, aggb, W2sT, W2nT, b2, nullptr, flags, h2, N);

  // ---- layer 3 (mean 32->32, f32 out) ----
  gather_sum32<<<gg,256,0,stream>>>(row_ptr, bucket, h2, ssum, N);
  mfma_mm<32,32,2,false,true,true,0><<<gc2,256,0,stream>>>(
      h2, ssum, W3sT, W3nT, b3, row_ptr, flags, d_out, N);
}

// Round 7
// 357.302 us; speedup vs baseline: 1.0711x; 1.0711x over previous
//
#include <hip/hip_runtime.h>
#include <hip/hip_bf16.h>

// GraphSAGE 3-layer: pool(64->64) -> pool(64->32) -> mean(32->32)
// R7: packed v_pk_max_u16 gather (post-relu bf16 >= 0 so u16 bit order ==
// value order; R6 gather_max64 was VALU-bound at 75% on unpack+max chain).
// Producers mask bit15 so -0.0 (0x8000) can never poison the u16 max.

typedef unsigned int uint;
typedef short short8 __attribute__((ext_vector_type(8)));
typedef float f32x4 __attribute__((ext_vector_type(4)));
typedef float f32x2 __attribute__((ext_vector_type(2)));
typedef unsigned short u16x8 __attribute__((ext_vector_type(8)));

__device__ __forceinline__ float bf2f(unsigned short h){
  return __uint_as_float(((uint)h) << 16);
}
__device__ __forceinline__ unsigned short f2bf(float f){
  uint u = __float_as_uint(f);
  u += 0x7fffu + ((u >> 16) & 1u);   // RNE
  return (unsigned short)(u >> 16);
}
__device__ __forceinline__ float lo16(uint u){ return __uint_as_float(u << 16); }
__device__ __forceinline__ float hi16(uint u){ return __uint_as_float(u & 0xffff0000u); }

__device__ __forceinline__ uint4 pkmax4(uint4 a, uint4 b){
  u16x8 x = __builtin_bit_cast(u16x8, a);
  u16x8 y = __builtin_bit_cast(u16x8, b);
  return __builtin_bit_cast(uint4, __builtin_elementwise_max(x, y));
}
__device__ __forceinline__ uint4 shflx4(uint4 a, int off){
  uint4 r;
  r.x = (uint)__shfl_xor((int)a.x, off, 64);
  r.y = (uint)__shfl_xor((int)a.y, off, 64);
  r.z = (uint)__shfl_xor((int)a.z, off, 64);
  r.w = (uint)__shfl_xor((int)a.w, off, 64);
  return r;
}

// flags[0]=1 if float inputs bf16 else f32; flags[1]=1 if edge_index int64.
// Also zeroes chist (saves a memset launch).
__global__ void detect_kernel(const unsigned short* x, const int* ei, int* flags,
                              uint* chist){
  int lane = threadIdx.x;  // 64 threads
  for (int i = lane; i < 1024; i += 64) chist[i] = 0;
  int sane = 0;
  #pragma unroll
  for (int k = 0; k < 4; ++k){
    int e = (x[(lane * 4 + k) * 2] >> 7) & 0xff;
    sane += (e >= 118 && e <= 134);
  }
  #pragma unroll
  for (int off = 32; off; off >>= 1) sane += __shfl_down(sane, off, 64);
  unsigned long long b = __ballot(ei[1 + 2 * lane] != 0);
  if (lane == 0){ flags[0] = (sane >= 128); flags[1] = (b == 0ull); }
}

// ---------------- weight prep: bf16 + transpose to WT[C][K] ----------------
struct WConv {
  const void* src[13];
  int n[13], isbias[13], Cs[13], K[13], off[13];
};

__global__ void conv_w(WConv wc, unsigned short* wtbase, float* bbase,
                       const int* flags){
  int t = blockIdx.x, n = wc.n[t];
  int isbf = flags[0];
  if (wc.isbias[t]){
    float* d = bbase + wc.off[t];
    for (int i = threadIdx.x; i < n; i += blockDim.x)
      d[i] = isbf ? bf2f(((const unsigned short*)wc.src[t])[i])
                  : ((const float*)wc.src[t])[i];
  } else {
    unsigned short* d = wtbase + wc.off[t];
    int Cs = wc.Cs[t], K = wc.K[t], Cm = (1 << Cs) - 1;
    for (int i = threadIdx.x; i < n; i += blockDim.x){
      int k = i >> Cs, c = i & Cm;
      unsigned short v = isbf ? ((const unsigned short*)wc.src[t])[i]
                              : f2bf(((const float*)wc.src[t])[i]);
      d[c * K + k] = v;
    }
  }
}

__device__ __forceinline__ void load_edge(const void* ei, int E, int is64, int e,
                                          int& s, int& d){
  if (is64){
    const long long* p = (const long long*)ei;
    s = (int)p[e]; d = (int)p[E + e];
  } else {
    const int* p = (const int*)ei;
    s = p[e]; d = p[E + e];
  }
}

// ---------------- CSR build ----------------
#define CSR_CE 8192

__global__ __launch_bounds__(256) void csr_phase0(
    const void* __restrict__ ei, const int* __restrict__ flags,
    uint* __restrict__ chist, int E, int N, int NB, int S)
{
  __shared__ uint h[1024];
  int is64 = flags[1], t = threadIdx.x;
  int e0 = blockIdx.x * CSR_CE;
  for (int i = t; i < 1024; i += 256) h[i] = 0;
  __syncthreads();
  #pragma unroll 4
  for (int it = 0; it < CSR_CE / 256; ++it){
    int e = e0 + it * 256 + t;
    if (e >= E) break;
    int s, d; load_edge(ei, E, is64, e, s, d);
    if ((unsigned)s >= (unsigned)N || (unsigned)d >= (unsigned)N) continue;
    atomicAdd(&h[d >> S], 1u);
  }
  __syncthreads();
  for (int i = t; i < NB; i += 256){ uint c = h[i]; if (c) atomicAdd(chist + i, c); }
}

__global__ void csr_scan0(const uint* __restrict__ chist, int* __restrict__ cbase,
                          int* __restrict__ ccur, int* __restrict__ rowptrN, int NB)
{
  __shared__ int sm[256];
  int t = threadIdx.x;
  int g = (NB + 255) / 256;          // <= 4
  int vb = t * g, v[4], s = 0;
  for (int k = 0; k < g; ++k){
    int i = vb + k; int x = (i < NB) ? (int)chist[i] : 0; v[k] = x; s += x;
  }
  sm[t] = s; __syncthreads();
  for (int off = 1; off < 256; off <<= 1){
    int x = (t >= off) ? sm[t - off] : 0;
    __syncthreads(); sm[t] += x; __syncthreads();
  }
  int run = sm[t] - s;
  for (int k = 0; k < g; ++k){
    int i = vb + k;
    if (i < NB){ cbase[i] = run; ccur[i] = run; run += v[k]; }
  }
  if (t == 255){ cbase[NB] = run; *rowptrN = run; }
}

// phase1: multisplit to coarse buckets; packed pair = (src<<S)|(dst&(2^S-1)).
__global__ __launch_bounds__(256) void csr_phase1(
    const void* __restrict__ ei, const int* __restrict__ flags,
    int* __restrict__ ccur, uint* __restrict__ pairs,
    int E, int N, int NB, int S)
{
  __shared__ uint hist[1024];
  __shared__ uint gbase[1024];
  int is64 = flags[1];
  int t = threadIdx.x;
  uint dmask = (1u << S) - 1u;
  int e0 = blockIdx.x * CSR_CE;
  for (int i = t; i < 1024; i += 256) hist[i] = 0;
  __syncthreads();
  #pragma unroll 4
  for (int it = 0; it < CSR_CE / 256; ++it){
    int e = e0 + it * 256 + t;
    if (e >= E) break;
    int s, d; load_edge(ei, E, is64, e, s, d);
    if ((unsigned)s >= (unsigned)N || (unsigned)d >= (unsigned)N) continue;
    atomicAdd(&hist[d >> S], 1u);
  }
  __syncthreads();
  for (int b = t; b < NB; b += 256){
    uint c = hist[b];
    if (c) gbase[b] = (uint)atomicAdd(&ccur[b], (int)c);
    hist[b] = 0;
  }
  __syncthreads();
  #pragma unroll 4
  for (int it = 0; it < CSR_CE / 256; ++it){
    int e = e0 + it * 256 + t;
    if (e >= E) break;
    int s, d; load_edge(ei, E, is64, e, s, d);
    if ((unsigned)s >= (unsigned)N || (unsigned)d >= (unsigned)N) continue;
    int b = d >> S;
    uint local = atomicAdd(&hist[b], 1u);
    pairs[gbase[b] + local] = ((uint)s << S) | ((uint)d & dmask);
  }
}

// phase2: per-bucket hist+scan in LDS -> row_ptr slice, exact placement.
#define P2_CAP 6144
__global__ __launch_bounds__(256) void csr_phase2(
    const int* __restrict__ cbase, const uint* __restrict__ pairs,
    int* __restrict__ bucket, int* __restrict__ row_ptr, int N, int S)
{
  __shared__ int lbuf[P2_CAP];
  __shared__ int cur[1024];
  __shared__ int sm[256];
  int b = blockIdx.x, t = threadIdx.x;
  uint dmask = (1u << S) - 1u;
  int n0 = b << S;
  int n1 = n0 + (1 << S); if (n1 > N) n1 = N;
  int nn = n1 - n0;
  int base = cbase[b], end = cbase[b + 1], cnt = end - base;

  for (int i = t; i < nn; i += 256) cur[i] = 0;
  __syncthreads();
  for (int j = base + t; j < end; j += 256)
    atomicAdd(&cur[(int)(pairs[j] & dmask)], 1);
  __syncthreads();
  int g = (nn + 255) / 256, vb = t * g, v[4], s = 0;
  for (int k = 0; k < g; ++k){
    int i = vb + k; int x = (i < nn) ? cur[i] : 0; v[k] = x; s += x;
  }
  sm[t] = s; __syncthreads();
  for (int off = 1; off < 256; off <<= 1){
    int x = (t >= off) ? sm[t - off] : 0;
    __syncthreads(); sm[t] += x; __syncthreads();
  }
  int run = sm[t] - s;
  for (int k = 0; k < g; ++k){
    int i = vb + k;
    if (i < nn){ row_ptr[n0 + i] = base + run; cur[i] = run; run += v[k]; }
  }
  __syncthreads();
  if (cnt <= 0) return;
  if (cnt <= P2_CAP){
    for (int j = base + t; j < end; j += 256){
      uint pr = pairs[j];
      int pos = atomicAdd(&cur[(int)(pr & dmask)], 1);
      lbuf[pos] = (int)(pr >> S);
    }
    __syncthreads();
    for (int i = t; i < cnt; i += 256) bucket[base + i] = lbuf[i];
  } else {
    for (int j = base + t; j < end; j += 256){
      uint pr = pairs[j];
      int pos = atomicAdd(&cur[(int)(pr & dmask)], 1);
      bucket[base + pos] = (int)(pr >> S);
    }
  }
}

// ---------------- gather-reduce ----------------
// wave per node. fg8=(lane&7)*8 features (uint4=16B); rowsel=lane>>3 ->
// 8 rows per load. Packed u16 max on raw bf16 bits (values >= 0, no -0.0).
__global__ __launch_bounds__(256) void gather_max64(
    const int* __restrict__ row_ptr, const int* __restrict__ bucket,
    const unsigned short* __restrict__ m, unsigned short* __restrict__ agg, int N)
{
  int node = (int)((blockIdx.x * 256u + threadIdx.x) >> 6);
  int lane = threadIdx.x & 63;
  if (node >= N) return;
  int rs = row_ptr[node], cnt = row_ptr[node + 1] - rs;
  int fg8 = (lane & 7) * 8, rowsel = lane >> 3;
  uint4 acc = {0u, 0u, 0u, 0u};
  for (int c0 = 0; c0 < cnt; c0 += 64){
    int chunk = min(cnt - c0, 64);
    int bval = (lane < chunk) ? bucket[rs + c0 + lane] : 0;
    int j = 0;
    for (; j + 16 <= chunk; j += 16){
      int s0 = __shfl(bval, j + rowsel, 64);
      int s1 = __shfl(bval, j + 8 + rowsel, 64);
      uint4 v0 = *(const uint4*)(m + (size_t)s0 * 64 + fg8);
      uint4 v1 = *(const uint4*)(m + (size_t)s1 * 64 + fg8);
      acc = pkmax4(acc, pkmax4(v0, v1));
    }
    for (; j + 8 <= chunk; j += 8){
      int s0 = __shfl(bval, j + rowsel, 64);
      uint4 v0 = *(const uint4*)(m + (size_t)s0 * 64 + fg8);
      acc = pkmax4(acc, v0);
    }
    if (j < chunk){
      int jj = j + rowsel;
      int s = __shfl(bval, jj < chunk ? jj : j, 64);
      if (jj < chunk){
        uint4 v = *(const uint4*)(m + (size_t)s * 64 + fg8);
        acc = pkmax4(acc, v);
      }
    }
  }
  #pragma unroll
  for (int off = 8; off <= 32; off <<= 1) acc = pkmax4(acc, shflx4(acc, off));
  if (lane < 8) *(uint4*)(agg + (size_t)node * 64 + fg8) = acc;
}

// wave per node; 64B rows. fg8=(lane&3)*8; rowsel=lane>>2 -> 16 rows/load.
// f32x2 packed adds; 2x unroll for MLP.
__device__ __forceinline__ f32x2 b2lo(uint u){
  f32x2 r; r.x = lo16(u); r.y = hi16(u); return r;
}
__global__ __launch_bounds__(256) void gather_sum32(
    const int* __restrict__ row_ptr, const int* __restrict__ bucket,
    const unsigned short* __restrict__ h2, unsigned short* __restrict__ ssum, int N)
{
  int node = (int)((blockIdx.x * 256u + threadIdx.x) >> 6);
  int lane = threadIdx.x & 63;
  if (node >= N) return;
  int rs = row_ptr[node], cnt = row_ptr[node + 1] - rs;
  int fg8 = (lane & 3) * 8, rowsel = lane >> 2;
  f32x2 a01 = {0.f, 0.f}, a23 = {0.f, 0.f}, a45 = {0.f, 0.f}, a67 = {0.f, 0.f};
  for (int c0 = 0; c0 < cnt; c0 += 64){
    int chunk = min(cnt - c0, 64);
    int bval = (lane < chunk) ? bucket[rs + c0 + lane] : 0;
    int j = 0;
    for (; j + 32 <= chunk; j += 32){
      int s0 = __shfl(bval, j + rowsel, 64);
      int s1 = __shfl(bval, j + 16 + rowsel, 64);
      uint4 v0 = *(const uint4*)(h2 + (size_t)s0 * 32 + fg8);
      uint4 v1 = *(const uint4*)(h2 + (size_t)s1 * 32 + fg8);
      a01 += b2lo(v0.x) + b2lo(v1.x); a23 += b2lo(v0.y) + b2lo(v1.y);
      a45 += b2lo(v0.z) + b2lo(v1.z); a67 += b2lo(v0.w) + b2lo(v1.w);
    }
    for (; j + 16 <= chunk; j += 16){
      int s0 = __shfl(bval, j + rowsel, 64);
      uint4 v0 = *(const uint4*)(h2 + (size_t)s0 * 32 + fg8);
      a01 += b2lo(v0.x); a23 += b2lo(v0.y); a45 += b2lo(v0.z); a67 += b2lo(v0.w);
    }
    if (j < chunk){
      int jj = j + rowsel;
      int s = __shfl(bval, jj < chunk ? jj : j, 64);
      if (jj < chunk){
        uint4 v = *(const uint4*)(h2 + (size_t)s * 32 + fg8);
        a01 += b2lo(v.x); a23 += b2lo(v.y); a45 += b2lo(v.z); a67 += b2lo(v.w);
      }
    }
  }
  #pragma unroll
  for (int off = 4; off <= 32; off <<= 1){
    a01.x += __shfl_xor(a01.x, off, 64); a01.y += __shfl_xor(a01.y, off, 64);
    a23.x += __shfl_xor(a23.x, off, 64); a23.y += __shfl_xor(a23.y, off, 64);
    a45.x += __shfl_xor(a45.x, off, 64); a45.y += __shfl_xor(a45.y, off, 64);
    a67.x += __shfl_xor(a67.x, off, 64); a67.y += __shfl_xor(a67.y, off, 64);
  }
  if (lane < 4){
    uint4 pk;
    pk.x = (uint)f2bf(a01.x) | ((uint)f2bf(a01.y) << 16);
    pk.y = (uint)f2bf(a23.x) | ((uint)f2bf(a23.y) << 16);
    pk.z = (uint)f2bf(a45.x) | ((uint)f2bf(a45.y) << 16);
    pk.w = (uint)f2bf(a67.x) | ((uint)f2bf(a67.y) << 16);
    *(uint4*)(ssum + (size_t)node * 32 + fg8) = pk;
  }
}

// ---------------- MFMA dense transforms ----------------
__device__ __forceinline__ short8 ld_fragA_bf16(const unsigned short* A, int row,
                                                int K, int koff){
  return *(const short8*)(A + (size_t)row * K + koff);
}
__device__ __forceinline__ short8 ld_fragA_f32(const float* A, int row,
                                               int K, int koff){
  const float* q = A + (size_t)row * K + koff;
  float4 f0 = *(const float4*)q;
  float4 f1 = *(const float4*)(q + 4);
  short8 r;
  r[0] = (short)f2bf(f0.x); r[1] = (short)f2bf(f0.y);
  r[2] = (short)f2bf(f0.z); r[3] = (short)f2bf(f0.w);
  r[4] = (short)f2bf(f1.x); r[5] = (short)f2bf(f1.y);
  r[6] = (short)f2bf(f1.z); r[7] = (short)f2bf(f1.w);
  return r;
}
// relu bf16 with -0.0 (0x8000) squashed so packed-u16 max stays exact.
__device__ __forceinline__ unsigned short f2bf_relu(float f){
  return (unsigned short)(f2bf(fmaxf(f, 0.f)) & 0x7fff);
}

// KA in {32,64}; KB in {0,32,64}; CT = C/16 in {2,4}; AMODE: 0=bf16, 2=runtime.
template<int KA, int KB, int CT, bool RELU, bool MEAN, bool OUTF32, int AMODE>
__global__ __launch_bounds__(256) void mfma_mm(
    const void* __restrict__ Av, const unsigned short* __restrict__ Bv,
    const unsigned short* __restrict__ WaT, const unsigned short* __restrict__ WbT,
    const float* __restrict__ bias, const int* __restrict__ row_ptr,
    const int* __restrict__ flags, void* __restrict__ outv, int N)
{
  constexpr int C = CT * 16;
  int wid = threadIdx.x >> 6, lane = threadIdx.x & 63;
  int g = blockIdx.x * 4 + wid;
  int rt, ct;
  if constexpr (CT == 4){ rt = g >> 2; ct = g & 3; }
  else                  { rt = g >> 1; ct = g & 1; }
  int RT = (N + 15) >> 4;
  if (rt >= RT) return;
  int m = lane & 15, quad = lane >> 4;
  int row = rt * 16 + m;
  int rowc = row < N ? row : N - 1;
  int colbase = ct * 16;
  int koq = quad * 8;

  bool af32 = (AMODE == 2) && (flags[0] == 0);
  f32x4 accS = {0.f, 0.f, 0.f, 0.f};
  f32x4 accA = {0.f, 0.f, 0.f, 0.f};

  #pragma unroll
  for (int k0 = 0; k0 < KA; k0 += 32){
    short8 af = af32 ? ld_fragA_f32((const float*)Av, rowc, KA, k0 + koq)
                     : ld_fragA_bf16((const unsigned short*)Av, rowc, KA, k0 + koq);
    short8 wf = *(const short8*)(WaT + (size_t)(colbase + m) * KA + k0 + koq);
    accS = __builtin_amdgcn_mfma_f32_16x16x32_bf16(af, wf, accS, 0, 0, 0);
  }
  if constexpr (KB > 0){
    #pragma unroll
    for (int k0 = 0; k0 < KB; k0 += 32){
      short8 bf = ld_fragA_bf16(Bv, rowc, KB, k0 + koq);
      short8 wf = *(const short8*)(WbT + (size_t)(colbase + m) * KB + k0 + koq);
      if constexpr (MEAN)
        accA = __builtin_amdgcn_mfma_f32_16x16x32_bf16(bf, wf, accA, 0, 0, 0);
      else
        accS = __builtin_amdgcn_mfma_f32_16x16x32_bf16(bf, wf, accS, 0, 0, 0);
    }
  }
  float bv = bias[colbase + m];
  #pragma unroll
  for (int r = 0; r < 4; ++r){
    int orow = rt * 16 + quad * 4 + r;
    if (orow >= N) continue;
    float v = accS[r] + bv;
    if constexpr (MEAN){
      int dg = row_ptr[orow + 1] - row_ptr[orow];
      v += accA[r] * (1.f / fmaxf((float)dg, 1.f));
    }
    if constexpr (OUTF32){
      if constexpr (RELU) v = fmaxf(v, 0.f);
      ((float*)outv)[(size_t)orow * C + colbase + m] = v;
    } else {
      unsigned short o;
      if constexpr (RELU) o = f2bf_relu(v);
      else                o = f2bf(v);
      ((unsigned short*)outv)[(size_t)orow * C + colbase + m] = o;
    }
  }
}

// Fused: h1 = relu(A@WaT^T + B@WbT^T + b1) [C=64, bf16 out1], then
// mbuf2 = relu(h1@WcT^T + b2p) [C=64, bf16 out2]. Block = 4 waves = one
// 16-row tile; h1 tile round-trips through LDS (C/D -> A-frag layout).
template<int AMODE>
__global__ __launch_bounds__(256) void mfma_mm_fused(
    const void* __restrict__ Av, const unsigned short* __restrict__ Bv,
    const unsigned short* __restrict__ WaT, const unsigned short* __restrict__ WbT,
    const float* __restrict__ bias1,
    const unsigned short* __restrict__ WcT, const float* __restrict__ bias2,
    const int* __restrict__ flags,
    unsigned short* __restrict__ out1, unsigned short* __restrict__ out2, int N)
{
  constexpr int K = 64, C = 64, LDH = 72;   // 144B row stride: 16B-aligned
  __shared__ unsigned short hl[16 * LDH];
  int wid = threadIdx.x >> 6, lane = threadIdx.x & 63;
  int rt = blockIdx.x;
  int m = lane & 15, quad = lane >> 4;
  int row = rt * 16 + m;
  int rowc = row < N ? row : N - 1;
  int colbase = wid * 16;
  int koq = quad * 8;
  bool af32 = (AMODE == 2) && (flags[0] == 0);

  f32x4 acc = {0.f, 0.f, 0.f, 0.f};
  #pragma unroll
  for (int k0 = 0; k0 < K; k0 += 32){
    short8 af = af32 ? ld_fragA_f32((const float*)Av, rowc, K, k0 + koq)
                     : ld_fragA_bf16((const unsigned short*)Av, rowc, K, k0 + koq);
    short8 wf = *(const short8*)(WaT + (size_t)(colbase + m) * K + k0 + koq);
    acc = __builtin_amdgcn_mfma_f32_16x16x32_bf16(af, wf, acc, 0, 0, 0);
    short8 bf = ld_fragA_bf16(Bv, rowc, K, k0 + koq);
    short8 wg = *(const short8*)(WbT + (size_t)(colbase + m) * K + k0 + koq);
    acc = __builtin_amdgcn_mfma_f32_16x16x32_bf16(bf, wg, acc, 0, 0, 0);
  }
  float bv = bias1[colbase + m];
  #pragma unroll
  for (int r = 0; r < 4; ++r){
    int rl = quad * 4 + r;
    int orow = rt * 16 + rl;
    unsigned short hb = f2bf_relu(acc[r] + bv);
    hl[rl * LDH + colbase + m] = hb;
    if (orow < N) out1[(size_t)orow * C + colbase + m] = hb;
  }
  __syncthreads();
  f32x4 acc2 = {0.f, 0.f, 0.f, 0.f};
  #pragma unroll
  for (int k0 = 0; k0 < K; k0 += 32){
    short8 af = *(const short8*)(hl + m * LDH + k0 + koq);
    short8 wf = *(const short8*)(WcT + (size_t)(colbase + m) * K + k0 + koq);
    acc2 = __builtin_amdgcn_mfma_f32_16x16x32_bf16(af, wf, acc2, 0, 0, 0);
  }
  float b2v = bias2[colbase + m];
  #pragma unroll
  for (int r = 0; r < 4; ++r){
    int orow = rt * 16 + quad * 4 + r;
    if (orow < N)
      out2[(size_t)orow * C + colbase + m] = f2bf_relu(acc2[r] + b2v);
  }
}

static inline char* align256(char* p){
  return (char*)(((uintptr_t)p + 255) & ~(uintptr_t)255);
}

extern "C" void kernel_launch(void* const* d_in, const int* in_sizes, int n_in,
                              void* d_out, int out_size, void* d_ws, size_t ws_size,
                              hipStream_t stream)
{
  const void* x = d_in[0];
  const void* ei = d_in[1];
  int N = in_sizes[0] / 64;   // 100000
  int E = in_sizes[1] / 2;    // 1600000

  char* ws = (char*)d_ws;
  unsigned short* wtbase = (unsigned short*)ws;     // 22528 ushorts (45KB)
  float* bbase = (float*)(ws + 65536);              // 256 floats
  int* flags = (int*)(ws + 131072 - 256);

  int S = 7, NB = (N + 127) >> 7;
  while (NB > 1024){ S++; NB = (N + (1 << S) - 1) >> S; }

  char* p = ws + 131072;
  int* row_ptr = (int*)p; p = align256(p + (size_t)(N + 1) * 4);
  uint* chist  = (uint*)p; p = align256(p + 4352);
  int* cbase   = (int*)p; p = align256(p + 4352);
  int* ccur    = (int*)p; p = align256(p + 4352);
  int* bucket  = (int*)p; p = align256(p + (size_t)E * 4);
  char* P = p;  p = align256(p + (size_t)N * 64 * 2);   // pairs(E*4)/mbuf/h2
  char* Q = p;  p = align256(p + (size_t)N * 64 * 2);   // aggb/ssum
  char* R = p;  p = align256(p + (size_t)N * 64 * 2);   // h1
  uint* pairs = (uint*)P;                               // E*4 <= N*128
  unsigned short* mbuf = (unsigned short*)P;
  unsigned short* h2   = (unsigned short*)P;   // after mbuf dead
  unsigned short* aggb = (unsigned short*)Q;
  unsigned short* ssum = (unsigned short*)Q;   // after aggb dead
  unsigned short* h1   = (unsigned short*)R;

  hipLaunchKernelGGL(detect_kernel, dim3(1), dim3(64), 0, stream,
                     (const unsigned short*)x, (const int*)ei, flags, chist);

  WConv wc;
  {
    const int widx[13] = {2, 3, 4, 5, 6, 7, 8, 9, 10, 11, 12, 13, 14};
    const int isb[13]  = {0, 1, 0, 0, 1, 0, 1, 0, 0, 1, 0, 0, 1};
    const int Cs[13]   = {6, 0, 6, 6, 0, 6, 0, 5, 5, 0, 5, 5, 0};
    const int Kk[13]   = {64, 0, 64, 64, 0, 64, 0, 64, 64, 0, 32, 32, 0};
    const int off[13]  = {0, 0, 4096, 8192, 64, 12288, 128, 16384, 18432, 192,
                          20480, 21504, 224};
    for (int i = 0; i < 13; ++i){
      wc.src[i] = d_in[widx[i]]; wc.n[i] = in_sizes[widx[i]];
      wc.isbias[i] = isb[i]; wc.Cs[i] = Cs[i]; wc.K[i] = Kk[i]; wc.off[i] = off[i];
    }
  }
  hipLaunchKernelGGL(conv_w, dim3(13), dim3(256), 0, stream, wc, wtbase, bbase, flags);
  unsigned short* W1pT = wtbase + 0;     unsigned short* W1sT = wtbase + 4096;
  unsigned short* W1nT = wtbase + 8192;  unsigned short* W2pT = wtbase + 12288;
  unsigned short* W2sT = wtbase + 16384; unsigned short* W2nT = wtbase + 18432;
  unsigned short* W3sT = wtbase + 20480; unsigned short* W3nT = wtbase + 21504;
  float* b1p = bbase + 0;  float* b1 = bbase + 64; float* b2p = bbase + 128;
  float* b2 = bbase + 192; float* b3 = bbase + 224;

  // ---- CSR build ----
  int nP = (E + CSR_CE - 1) / CSR_CE;
  csr_phase0<<<nP, 256, 0, stream>>>(ei, flags, chist, E, N, NB, S);
  csr_scan0<<<1, 256, 0, stream>>>(chist, cbase, ccur, row_ptr + N, NB);
  csr_phase1<<<nP, 256, 0, stream>>>(ei, flags, ccur, pairs, E, N, NB, S);
  csr_phase2<<<NB, 256, 0, stream>>>(cbase, pairs, bucket, row_ptr, N, S);

  int RT = (N + 15) / 16;
  int gc2 = (RT * 2 + 3) / 4;   // CT=2 kernels
  int gg = (N + 3) / 4;         // gathers: 4 nodes (waves) per block

  // ---- layer 1 (pool 64->64, relu) + layer-2 pool transform fused ----
  mfma_mm<64,0,4,true,false,false,2><<<RT,256,0,stream>>>(
      x, nullptr, W1pT, nullptr, b1p, nullptr, flags, mbuf, N);
  gather_max64<<<gg,256,0,stream>>>(row_ptr, bucket, mbuf, aggb, N);
  mfma_mm_fused<2><<<RT,256,0,stream>>>(
      x, aggb, W1sT, W1nT, b1, W2pT, b2p, flags, h1, mbuf, N);

  // ---- layer 2 (pool 64->32) ----
  gather_max64<<<gg,256,0,stream>>>(row_ptr, bucket, mbuf, aggb, N);
  mfma_mm<64,64,2,false,false,false,0><<<gc2,256,0,stream>>>(
      h1, aggb, W2sT, W2nT, b2, nullptr, flags, h2, N);

  // ---- layer 3 (mean 32->32, f32 out) ----
  gather_sum32<<<gg,256,0,stream>>>(row_ptr, bucket, h2, ssum, N);
  mfma_mm<32,32,2,false,true,true,0><<<gc2,256,0,stream>>>(
      h2, ssum, W3sT, W3nT, b3, row_ptr, flags, d_out, N);
}